// Round 8
// baseline (56138.464 us; speedup 1.0000x reference)
//
#include <hip/hip_runtime.h>
#include <math.h>

#define NBLK    16          // worker blocks, all on ONE XCD
#define NLAUNCH 256         // launched blocks; non-elected exit immediately
#define BS      1024
#define NSTATE  17
#define NH      256
#define NX      273         // NH + NSTATE
#define WID     1024
#define NT      64
#define NSUB    8
#define ROWS_H  (WID/NBLK)  // 64 rows/block for 1024-wide layers
#define ROWS_L  (NH/NBLK)   // 16 rows/block for the 256-wide output layer
#define POLL_CAP 2000000    // fail fast instead of hanging

typedef unsigned long long u64;
typedef unsigned int u32;

__device__ __forceinline__ float softplus_f(float v) {
    return fmaxf(v, 0.f) + log1pf(expf(-fabsf(v)));
}

// ---- tagged-word atomic exchange (same-XCD L2) ----------------------------
// R5-proven transport (bit-exact absmax 1.22e-4, stable timing): every value
// travels as one 8B word {tag^bits:32 | bits:32} through the L2 atomic units
// (atomics never execute in L1 -> can never be stale; XOR-entanglement makes
// any tear self-detecting). The DATA POLL IS THE WAIT -- R6/R7's separate
// arrival flags created RMW convoys on hot lines (44-75ms, high variance).
// Tag = tagbase(nonce from election) + monotone round R.
__device__ __forceinline__ void st_tag(u64* p, float v, unsigned tag) {
    unsigned lo = __float_as_uint(v);
    u64 w = ((u64)(tag ^ lo) << 32) | (u64)lo;
    asm volatile("global_atomic_swap_x2 %0, %1, off" :: "v"(p), "v"(w) : "memory");
}
__device__ __forceinline__ u64 ld_tag(const u64* p) {
    u64 w;
    asm volatile("global_atomic_add_x2 %0, %1, %2, off sc0\n\t"
                 "s_waitcnt vmcnt(0)"
                 : "=&v"(w) : "v"(p), "v"(0ULL) : "memory");
    return w;
}
__device__ __forceinline__ bool tag_ok(u64 w, unsigned tag) {
    return (((u32)(w >> 32)) ^ ((u32)w)) == tag;
}

// Poll the 1024-word buffer into LDS; thread t owns exactly ONE word.
// Entry barrier: no thread may overwrite z_s while another still reads the
// previous layer's values. Lanes whose word arrived stop issuing RMWs.
__device__ __forceinline__ void consume_z(const u64* __restrict__ buf,
                                          unsigned tag,
                                          float* __restrict__ z_s, int t) {
    __syncthreads();
    const u64* p = buf + t;
    u64 w; int it = 0;
    do { w = ld_tag(p); } while (!tag_ok(w, tag) && ++it < POLL_CAP);
    z_s[t] = __uint_as_float((u32)w);
    __syncthreads();
}

extern "C" __global__ __launch_bounds__(BS, 4) void ode_kernel(
    const float* __restrict__ ts,   const float* __restrict__ W0,
    const float* __restrict__ b0,   const float* __restrict__ Wh,
    const float* __restrict__ bh,   const float* __restrict__ Wl,
    const float* __restrict__ bl,   const float* __restrict__ betaW,
    const float* __restrict__ betab,const float* __restrict__ hvec,
    const float* __restrict__ scale,const float* __restrict__ y0log,
    float* __restrict__ out, u64* zA64, u64* zB64, u64* dh64, unsigned* ctrl)
{
    const int t = threadIdx.x;

    __shared__ int      role_sh;
    __shared__ unsigned tagbase_sh;
    __shared__ float y_s[NX];
    __shared__ float yn_s[NX];
    __shared__ float xm[NX];     // MLP-ordered input: [h(256), state(17)]
    __shared__ float k_s[NX];
    __shared__ float z_s[WID];
    __shared__ float red[4];
    __shared__ float dt_sh;

    // ---- XCD election (MALL atomics, one-time): first XCD to register NBLK
    // blocks wins. 1024-thr blocks -> 1 block/CU; 256 blocks co-resident;
    // every XCD eventually counts 32 >= 16, so election cannot deadlock.
    // Winner word packs {realtime-nonce:28 | xcd+1:4}; doubles as tag base.
    if (t == 0) {
        int xcd;
        asm volatile("s_getreg_b32 %0, hwreg(HW_REG_XCC_ID)" : "=s"(xcd));
        xcd &= 7;
        unsigned rk = atomicAdd(&ctrl[xcd], 1u);
        if (rk == NBLK - 1) {
            u64 rt;
            asm volatile("s_memrealtime %0\n\ts_waitcnt lgkmcnt(0)" : "=s"(rt));
            unsigned word = (((unsigned)(rt >> 4)) << 4) | (unsigned)(xcd + 1);
            atomicCAS(&ctrl[8], 0u, word);
        }
        unsigned w; int it = 0;
        do {
            w = __hip_atomic_load(&ctrl[8], __ATOMIC_RELAXED, __HIP_MEMORY_SCOPE_AGENT);
        } while (w == 0u && ++it < POLL_CAP);
        role_sh    = (w != 0u && xcd == (int)(w & 0xFu) - 1 && rk < NBLK) ? (int)rk : -1;
        tagbase_sh = w;
    }
    __syncthreads();
    const int blk = role_sh;
    const unsigned tagbase = tagbase_sh;
    if (blk < 0) return;

    const float scale0 = scale[0];
    const float betab0 = betab[0];
    unsigned R = 0;   // exchange round; identical sequence on all workers

    const int rowH = t >> 4, laneH = t & 15;    // 64 rows x 16 lanes
    const int growH = blk * ROWS_H + rowH;
    const int rowL = t >> 6, laneL = t & 63;    // 16 rows x 64 lanes
    const int growL = blk * ROWS_L + rowL;

    // ---- loop-invariant scalars ----
    const float b0r = b0[growH];
    float bhr[3];
    bhr[0] = bh[growH]; bhr[1] = bh[WID + growH]; bhr[2] = bh[2 * WID + growH];
    const float blr    = bl[growL];
    const float betaWr = (t < NH) ? betaW[t] : 0.f;
    const float* wh0p = Wh + (size_t)growH * WID + laneH * 4;
    const float* wh1p = wh0p + (size_t)WID * WID;
    const float* wh2p = wh1p + (size_t)WID * WID;
    const float* wlp  = Wl + (size_t)growL * WID + laneL * 4;

    // W0 slice: 18 regs (covers 273 cols at stride 16)
    float w0r[18];
    {
        const float* w0p = W0 + (size_t)growH * NX;
        #pragma unroll
        for (int i = 0; i < 18; i++) {
            int c = laneH + i * 16;
            w0r[i] = (c < NX) ? w0p[c] : 0.f;
        }
    }

    // ---- y0 = [softmax(y0_log), hvec] ----
    if (t < NSTATE) {
        float m = -1e30f;
        for (int j = 0; j < NSTATE; j++) m = fmaxf(m, y0log[j]);
        float ssum = 0.f;
        for (int j = 0; j < NSTATE; j++) ssum += expf(y0log[j] - m);
        y_s[t] = expf(y0log[t] - m) / ssum;
    }
    if (t < NH) y_s[NSTATE + t] = hvec[t];
    __syncthreads();

    if (blk == 0) {
        if (t < NSTATE) out[t] = y_s[t];
        if (t < NH)     out[NT * NSTATE + t] = y_s[NSTATE + t];
    }

    const float c_xi = 13.f / 12.f, c_mu = 0.041f / 12.f, c_sig = 91.f / 12.f,
                c_nu = 36.f / 12.f, c_gam = 1.8f / 12.f;

    for (int iv = 0; iv < NT - 1; iv++) {
        if (t == 0) dt_sh = (ts[iv + 1] - ts[iv]) * (1.f / NSUB);
        __syncthreads();
        const float dt = dt_sh;

        for (int sub = 0; sub < NSUB; sub++) {
            if (t < NX) yn_s[t] = y_s[t];

            for (int s = 0; s < 4; s++) {
                const float a   = (s == 0) ? 0.f : ((s == 3) ? 1.f : 0.5f);
                const float wgt = ((s == 0) || (s == 3)) ? dt * (1.f / 6.f) : dt * (1.f / 3.f);
                const float adt = a * dt;

                // ---- stage input, built directly in MLP order [h, state] ----
                if (t < NX) {
                    const int src = (t < NH) ? (NSTATE + t) : (t - NH);
                    float v = y_s[src];
                    if (s != 0) v = fmaf(adt, k_s[src], v);
                    xm[t] = v;
                }
                __syncthreads();

                // ---- L0: 1024x273, W0 in regs (fmaf-pinned) ----
                {
                    float acc = 0.f;
                    #pragma unroll
                    for (int i = 0; i < 18; i++) {
                        int c = laneH + i * 16;
                        if (c < NX) acc = fmaf(w0r[i], xm[c], acc);
                    }
                    #pragma unroll
                    for (int m = 1; m < 16; m <<= 1) acc += __shfl_xor(acc, m, 16);
                    ++R;
                    if (laneH == 0) st_tag(&zA64[growH], softplus_f(acc + b0r), tagbase + R);
                }

                // ---- beta head + dstate: overlaps other blocks' publishes ----
                {
                    if (t < NH) {
                        float p = betaWr * xm[t];
                        #pragma unroll
                        for (int m = 1; m < 64; m <<= 1) p += __shfl_xor(p, m, 64);
                        if ((t & 63) == 0) red[t >> 6] = p;
                    }
                    __syncthreads();
                    if (t == 0) {
                        const float* xs = xm + NH;
                        float sd  = red[0] + red[1] + red[2] + red[3] + betab0;
                        float bb1 = 8.f / (1.f + expf(-sd)) + 25.f;
                        float bb2 = 0.5f * bb1, bb3 = 0.35f * bb1, bb4 = 0.25f * bb1;
                        float M  = xs[0],  S1 = xs[1],  E1 = xs[2],  E2 = xs[3];
                        float E3 = xs[4],  E4 = xs[5],  I1 = xs[6],  I2 = xs[7];
                        float I3 = xs[8],  I4 = xs[9],  R1 = xs[10], R2 = xs[11];
                        float R3 = xs[12], R4 = xs[13], S2 = xs[14], S3 = xs[15];
                        float S4 = xs[16];
                        float I = I1 + I2 + I3 + I4, Rs = R1 + R2 + R3 + R4;
                        k_s[0]  = Rs * c_mu - (c_xi + c_mu) * M;
                        k_s[1]  = c_mu * (1.f - Rs) + c_xi * M - c_mu * S1 - bb1 * I * S1;
                        k_s[2]  = bb1 * I * S1 - (c_mu + c_sig) * E1;
                        k_s[3]  = bb2 * I * S2 - (c_mu + c_sig) * E2;
                        k_s[4]  = bb3 * I * S3 - (c_mu + c_sig) * E3;
                        k_s[5]  = bb4 * I * S4 - (c_mu + c_sig) * E4;
                        k_s[6]  = c_sig * E1 - (c_nu + c_mu) * I1;
                        k_s[7]  = c_sig * E2 - (c_nu + c_mu) * I2;
                        k_s[8]  = c_sig * E3 - (c_nu + c_mu) * I3;
                        k_s[9]  = c_sig * E4 - (c_nu + c_mu) * I4;
                        k_s[10] = c_nu * I1 - (c_mu + c_gam) * R1;
                        k_s[11] = c_nu * I2 - (c_mu + c_gam) * R2;
                        k_s[12] = c_nu * I3 - (c_mu + c_gam) * R3;
                        k_s[13] = c_nu * I4 - (c_mu + c_gam) * R4;
                        k_s[14] = c_gam * R1 - c_mu * S2 - bb2 * I * S2;
                        k_s[15] = c_gam * R2 - c_mu * S3 - bb3 * I * S3;
                        k_s[16] = c_gam * (R3 + R4) - c_mu * S4 - bb4 * I * S4;
                    }
                    // k_s[0..16] next read only after later consume barriers.
                }

                // ---- hidden layers: weights prefetched BEFORE the poll so the
                //      L2 fetch (~300cy) hides under the spin; dot fmaf-pinned.
                auto hidden = [&](const float* wp, const u64* zin64,
                                  u64* zout64, float bias) {
                    float4 wv[16];
                    #pragma unroll
                    for (int i = 0; i < 16; i++) wv[i] = *(const float4*)(wp + i * 64);

                    consume_z(zin64, tagbase + R, z_s, t);

                    float acc = 0.f;
                    #pragma unroll
                    for (int i = 0; i < 16; i++) {
                        float4 zv = *(const float4*)(z_s + (laneH * 4 + i * 64));
                        acc = fmaf(wv[i].x, zv.x, acc);
                        acc = fmaf(wv[i].y, zv.y, acc);
                        acc = fmaf(wv[i].z, zv.z, acc);
                        acc = fmaf(wv[i].w, zv.w, acc);
                    }
                    #pragma unroll
                    for (int m = 1; m < 16; m <<= 1) acc += __shfl_xor(acc, m, 16);
                    ++R;
                    if (laneH == 0) st_tag(&zout64[growH], softplus_f(acc + bias), tagbase + R);
                };

                hidden(wh0p, zA64, zB64, bhr[0]);
                hidden(wh1p, zB64, zA64, bhr[1]);
                hidden(wh2p, zA64, zB64, bhr[2]);

                // ---- Wl: 256x1024, 16 rows/block, 64 lanes/row; tanh ----
                {
                    float4 wvL[4];
                    #pragma unroll
                    for (int i = 0; i < 4; i++) wvL[i] = *(const float4*)(wlp + i * 256);

                    consume_z(zB64, tagbase + R, z_s, t);

                    float acc = 0.f;
                    #pragma unroll
                    for (int i = 0; i < 4; i++) {
                        float4 zv = *(const float4*)(z_s + (laneL * 4 + i * 256));
                        acc = fmaf(wvL[i].x, zv.x, acc);
                        acc = fmaf(wvL[i].y, zv.y, acc);
                        acc = fmaf(wvL[i].z, zv.z, acc);
                        acc = fmaf(wvL[i].w, zv.w, acc);
                    }
                    #pragma unroll
                    for (int m = 1; m < 64; m <<= 1) acc += __shfl_xor(acc, m, 64);
                    ++R;
                    if (laneL == 0)
                        st_tag(&dh64[growL], scale0 * tanhf(0.01f * (acc + blr)), tagbase + R);
                }

                // ---- gather dh (one word per thread t<256) ----
                {
                    if (t < NH) {
                        u64 w; int it = 0;
                        do { w = ld_tag(dh64 + t); }
                        while (!tag_ok(w, tagbase + R) && ++it < POLL_CAP);
                        k_s[NSTATE + t] = __uint_as_float((u32)w);
                    }
                    __syncthreads();
                    if (t < NX) yn_s[t] = fmaf(wgt, k_s[t], yn_s[t]);
                }
            } // stages

            __syncthreads();
            if (t < NX) y_s[t] = yn_s[t];
            __syncthreads();
        } // substeps

        if (blk == 0) {
            if (t < NSTATE) out[(iv + 1) * NSTATE + t] = y_s[t];
            if (t < NH)     out[NT * NSTATE + (iv + 1) * NH + t] = y_s[NSTATE + t];
        }
    } // intervals
}

extern "C" void kernel_launch(void* const* d_in, const int* in_sizes, int n_in,
                              void* d_out, int out_size, void* d_ws, size_t ws_size,
                              hipStream_t stream) {
    const float* ts    = (const float*)d_in[0];
    const float* W0    = (const float*)d_in[1];
    const float* b0    = (const float*)d_in[2];
    const float* Wh    = (const float*)d_in[3];
    const float* bh    = (const float*)d_in[4];
    const float* Wl    = (const float*)d_in[5];
    const float* bl    = (const float*)d_in[6];
    const float* betaW = (const float*)d_in[7];
    const float* betab = (const float*)d_in[8];
    const float* hvec  = (const float*)d_in[9];
    const float* scale = (const float*)d_in[10];
    const float* y0log = (const float*)d_in[11];
    float* out = (float*)d_out;

    u64*      zA64 = (u64*)d_ws;                          // 1024*8 = 8 KB
    u64*      zB64 = (u64*)((char*)d_ws + 8192);          // 8 KB
    u64*      dh64 = (u64*)((char*)d_ws + 16384);         // 256*8 = 2 KB
    unsigned* ctrl = (unsigned*)((char*)d_ws + 18432);    // cnt[8], winner word

    // zero tagged words + election state (tag 0 never matches nonce+R)
    hipMemsetAsync(d_ws, 0, 18432 + 64, stream);
    hipLaunchKernelGGL(ode_kernel, dim3(NLAUNCH), dim3(BS), 0, stream,
                       ts, W0, b0, Wh, bh, Wl, bl, betaW, betab, hvec, scale,
                       y0log, out, zA64, zB64, dh64, ctrl);
}

// Round 9
// 22796.823 us; speedup vs baseline: 2.4626x; 2.4626x over previous
//
#include <hip/hip_runtime.h>
#include <math.h>

#define NBLK    32          // worker blocks, all on ONE XCD (its 32 CUs)
#define NLAUNCH 256         // launched blocks; non-elected exit immediately
#define BS      512
#define NSTATE  17
#define NH      256
#define NX      273         // NH + NSTATE
#define WID     1024
#define NT      64
#define NSUB    8
#define ROWS_H  (WID/NBLK)  // 32 rows/block for 1024-wide layers
#define ROWS_L  (NH/NBLK)   // 8 rows/block for the 256-wide output layer
#define POLL_CAP 2000000    // fail fast instead of hanging

typedef unsigned long long u64;
typedef unsigned int u32;

__device__ __forceinline__ float softplus_f(float v) {
    return fmaxf(v, 0.f) + log1pf(expf(-fabsf(v)));
}

// ---- tagged-word atomic exchange (same-XCD L2), bf16x2-PACKED -------------
// R5-proven transport: values travel through the L2 atomic units (atomics
// never execute in L1 -> never stale; direct data-poll, no separate flags --
// R6/R7 showed flag-gating convoys). R8 showed BS=1024 kills weight
// residency (VGPR cap 64 -> 18GB HBM refetch); 32x512 is the unique shape
// where h1/h2 live in AGPRs and h3 in LDS.
// NEW (R9): one 8B word carries TWO adjacent rows as bf16(RNE):
//   lo32 = {bf16(row even):16 | bf16(row odd):16},  hi32 = tag ^ lo32.
// Poll volume drops 4x (512 words, 1/thread, was 1024 x 2/thread); publish
// halves (16 swaps/block). Tear/stale-proof exactly as before. dh stays f32
// (it is the integrated quantity).
__device__ __forceinline__ u32 bf16_rne(float x) {
    u32 u = __float_as_uint(x);
    return (u + 0x7FFFu + ((u >> 16) & 1u)) >> 16;
}
__device__ __forceinline__ void st_pack(u64* p, float ve, float vo, unsigned tag) {
    u32 lo = (bf16_rne(ve) << 16) | bf16_rne(vo);
    u64 w = ((u64)(tag ^ lo) << 32) | (u64)lo;
    asm volatile("global_atomic_swap_x2 %0, %1, off" :: "v"(p), "v"(w) : "memory");
}
__device__ __forceinline__ void st_tag(u64* p, float v, unsigned tag) {
    u32 lo = __float_as_uint(v);
    u64 w = ((u64)(tag ^ lo) << 32) | (u64)lo;
    asm volatile("global_atomic_swap_x2 %0, %1, off" :: "v"(p), "v"(w) : "memory");
}
__device__ __forceinline__ u64 ld_tag(const u64* p) {
    u64 w;
    asm volatile("global_atomic_add_x2 %0, %1, %2, off sc0\n\t"
                 "s_waitcnt vmcnt(0)"
                 : "=&v"(w) : "v"(p), "v"(0ULL) : "memory");
    return w;
}
__device__ __forceinline__ bool tag_ok(u64 w, unsigned tag) {
    return (((u32)(w >> 32)) ^ ((u32)w)) == tag;
}

// Wait + gather the 512-packed-word buffer into z_s[1024] (f32).
// Entry barrier: nobody may overwrite z_s while others still read the
// previous layer (latent race in R1-R7, fixed here).
__device__ __forceinline__ void consume_z(const u64* __restrict__ buf,
                                          unsigned tag,
                                          float* __restrict__ z_s, int t) {
    __syncthreads();
    const u64* p = buf + t;
    u64 w; int it = 0;
    do { w = ld_tag(p); } while (!tag_ok(w, tag) && ++it < POLL_CAP);
    u32 lo = (u32)w;
    z_s[2 * t]     = __uint_as_float(lo & 0xFFFF0000u);
    z_s[2 * t + 1] = __uint_as_float(lo << 16);
    __syncthreads();
}

extern "C" __global__ __launch_bounds__(BS, 2) void ode_kernel(
    const float* __restrict__ ts,   const float* __restrict__ W0,
    const float* __restrict__ b0,   const float* __restrict__ Wh,
    const float* __restrict__ bh,   const float* __restrict__ Wl,
    const float* __restrict__ bl,   const float* __restrict__ betaW,
    const float* __restrict__ betab,const float* __restrict__ hvec,
    const float* __restrict__ scale,const float* __restrict__ y0log,
    float* __restrict__ out, u64* zA64, u64* zB64, u64* dh64, unsigned* ctrl)
{
    const int t = threadIdx.x;

    __shared__ int      role_sh;
    __shared__ unsigned tagbase_sh;
    __shared__ float y_s[NX];
    __shared__ float yn_s[NX];
    __shared__ float xm[NX];     // MLP-ordered input: [h(256), state(17)]
    __shared__ float k_s[NX];
    __shared__ float z_s[WID];
    __shared__ float red[8];
    __shared__ float dt_sh;
    extern __shared__ float wh2[];   // dynamic: 32 rows x 1024 of layer-3 (128 KB)

    // ---- XCD election (MALL atomics, one-time): first XCD to register NBLK
    // blocks wins. ~137KB LDS -> 1 block/CU; all 256 launched co-resident.
    // Winner word packs {realtime-nonce:28 | xcd+1:4}; doubles as tag base.
    if (t == 0) {
        int xcd;
        asm volatile("s_getreg_b32 %0, hwreg(HW_REG_XCC_ID)" : "=s"(xcd));
        xcd &= 7;
        unsigned rk = atomicAdd(&ctrl[xcd], 1u);
        if (rk == NBLK - 1) {
            u64 rt;
            asm volatile("s_memrealtime %0\n\ts_waitcnt lgkmcnt(0)" : "=s"(rt));
            unsigned word = (((unsigned)(rt >> 4)) << 4) | (unsigned)(xcd + 1);
            atomicCAS(&ctrl[8], 0u, word);
        }
        unsigned w; int it = 0;
        do {
            w = __hip_atomic_load(&ctrl[8], __ATOMIC_RELAXED, __HIP_MEMORY_SCOPE_AGENT);
        } while (w == 0u && ++it < POLL_CAP);
        role_sh    = (w != 0u && xcd == (int)(w & 0xFu) - 1 && rk < NBLK) ? (int)rk : -1;
        tagbase_sh = w;
    }
    __syncthreads();
    const int blk = role_sh;
    const unsigned tagbase = tagbase_sh;
    if (blk < 0) return;

    const float scale0 = scale[0];
    const float betab0 = betab[0];
    unsigned R = 0;   // exchange round; identical sequence on all workers

    const int rowH = t >> 4, laneH = t & 15;
    const int growH = blk * ROWS_H + rowH;
    const int rowL = t >> 6, laneL = t & 63;
    const int growL = blk * ROWS_L + rowL;

    // packed word index for this thread's (even) row pair
    const int packIdx = blk * (ROWS_H / 2) + (rowH >> 1);

    // ---- loop-invariant scalars ----
    const float b0r = b0[growH];
    float bhr[3];
    bhr[0] = bh[growH]; bhr[1] = bh[WID + growH]; bhr[2] = bh[2 * WID + growH];
    const float blr    = bl[growL];
    const float betaWr = (t < NH) ? betaW[t] : 0.f;
    const float* wlp = Wl + (size_t)growL * WID + laneL * 4;

    // ---- weight residency: h1,h2 in VGPR/AGPR (compiler, proven R5),
    //      h3 slice in LDS (128KB), W0 in 18 regs, Wl streamed (L2).
    float4 wv0[16], wv1[16];
    {
        const float* whp = Wh + (size_t)growH * WID + laneH * 4;
        #pragma unroll
        for (int i = 0; i < 16; i++) wv0[i] = *(const float4*)(whp + i * 64);
        #pragma unroll
        for (int i = 0; i < 16; i++) wv1[i] = *(const float4*)(whp + WID * WID + i * 64);
    }
    {   // copy layer-3 row slice into LDS (coalesced float4)
        const float* src = Wh + 2 * (size_t)WID * WID + (size_t)blk * ROWS_H * WID;
        for (int i = t * 4; i < ROWS_H * WID; i += BS * 4)
            *(float4*)&wh2[i] = *(const float4*)&src[i];
    }
    float w0r[18];
    {
        const float* w0p = W0 + (size_t)growH * NX;
        #pragma unroll
        for (int i = 0; i < 18; i++) {
            int c = laneH + i * 16;
            w0r[i] = (c < NX) ? w0p[c] : 0.f;
        }
    }

    // ---- y0 = [softmax(y0_log), hvec] ----
    if (t < NSTATE) {
        float m = -1e30f;
        for (int j = 0; j < NSTATE; j++) m = fmaxf(m, y0log[j]);
        float ssum = 0.f;
        for (int j = 0; j < NSTATE; j++) ssum += expf(y0log[j] - m);
        y_s[t] = expf(y0log[t] - m) / ssum;
    }
    if (t < NH) y_s[NSTATE + t] = hvec[t];
    __syncthreads();

    if (blk == 0) {
        if (t < NSTATE) out[t] = y_s[t];
        if (t < NH)     out[NT * NSTATE + t] = y_s[NSTATE + t];
    }

    const float c_xi = 13.f / 12.f, c_mu = 0.041f / 12.f, c_sig = 91.f / 12.f,
                c_nu = 36.f / 12.f, c_gam = 1.8f / 12.f;

    for (int iv = 0; iv < NT - 1; iv++) {
        if (t == 0) dt_sh = (ts[iv + 1] - ts[iv]) * (1.f / NSUB);
        __syncthreads();
        const float dt = dt_sh;

        for (int sub = 0; sub < NSUB; sub++) {
            if (t < NX) yn_s[t] = y_s[t];

            for (int s = 0; s < 4; s++) {
                const float a   = (s == 0) ? 0.f : ((s == 3) ? 1.f : 0.5f);
                const float wgt = ((s == 0) || (s == 3)) ? dt * (1.f / 6.f) : dt * (1.f / 3.f);
                const float adt = a * dt;

                // ---- stage input, built directly in MLP order [h, state] ----
                if (t < NX) {
                    const int src = (t < NH) ? (NSTATE + t) : (t - NH);
                    float v = y_s[src];
                    if (s != 0) v = fmaf(adt, k_s[src], v);
                    xm[t] = v;
                }
                __syncthreads();

                // ---- L0: 1024x273, W0 in regs (fmaf-pinned) ----
                {
                    float acc = 0.f;
                    #pragma unroll
                    for (int i = 0; i < 18; i++) {
                        int c = laneH + i * 16;
                        if (c < NX) acc = fmaf(w0r[i], xm[c], acc);
                    }
                    #pragma unroll
                    for (int m = 1; m < 16; m <<= 1) acc += __shfl_xor(acc, m, 16);
                    float val = softplus_f(acc + b0r);
                    float vodd = __shfl(val, (t & 63) + 16, 64); // next row's val
                    ++R;
                    if ((t & 31) == 0) st_pack(&zA64[packIdx], val, vodd, tagbase + R);
                }

                // ---- beta head + dstate: overlaps other blocks' publishes ----
                {
                    if (t < NH) {
                        float p = betaWr * xm[t];
                        #pragma unroll
                        for (int m = 1; m < 64; m <<= 1) p += __shfl_xor(p, m, 64);
                        if ((t & 63) == 0) red[t >> 6] = p;
                    }
                    __syncthreads();
                    if (t == 0) {
                        const float* xs = xm + NH;
                        float sd  = red[0] + red[1] + red[2] + red[3] + betab0;
                        float bb1 = 8.f / (1.f + expf(-sd)) + 25.f;
                        float bb2 = 0.5f * bb1, bb3 = 0.35f * bb1, bb4 = 0.25f * bb1;
                        float M  = xs[0],  S1 = xs[1],  E1 = xs[2],  E2 = xs[3];
                        float E3 = xs[4],  E4 = xs[5],  I1 = xs[6],  I2 = xs[7];
                        float I3 = xs[8],  I4 = xs[9],  R1 = xs[10], R2 = xs[11];
                        float R3 = xs[12], R4 = xs[13], S2 = xs[14], S3 = xs[15];
                        float S4 = xs[16];
                        float I = I1 + I2 + I3 + I4, Rs = R1 + R2 + R3 + R4;
                        k_s[0]  = Rs * c_mu - (c_xi + c_mu) * M;
                        k_s[1]  = c_mu * (1.f - Rs) + c_xi * M - c_mu * S1 - bb1 * I * S1;
                        k_s[2]  = bb1 * I * S1 - (c_mu + c_sig) * E1;
                        k_s[3]  = bb2 * I * S2 - (c_mu + c_sig) * E2;
                        k_s[4]  = bb3 * I * S3 - (c_mu + c_sig) * E3;
                        k_s[5]  = bb4 * I * S4 - (c_mu + c_sig) * E4;
                        k_s[6]  = c_sig * E1 - (c_nu + c_mu) * I1;
                        k_s[7]  = c_sig * E2 - (c_nu + c_mu) * I2;
                        k_s[8]  = c_sig * E3 - (c_nu + c_mu) * I3;
                        k_s[9]  = c_sig * E4 - (c_nu + c_mu) * I4;
                        k_s[10] = c_nu * I1 - (c_mu + c_gam) * R1;
                        k_s[11] = c_nu * I2 - (c_mu + c_gam) * R2;
                        k_s[12] = c_nu * I3 - (c_mu + c_gam) * R3;
                        k_s[13] = c_nu * I4 - (c_mu + c_gam) * R4;
                        k_s[14] = c_gam * R1 - c_mu * S2 - bb2 * I * S2;
                        k_s[15] = c_gam * R2 - c_mu * S3 - bb3 * I * S3;
                        k_s[16] = c_gam * (R3 + R4) - c_mu * S4 - bb4 * I * S4;
                    }
                    // k_s[0..16] next read only after later consume barriers.
                }

                // ---- h1, h2: weights in registers (fmaf-pinned) ----
                auto hidden = [&](const float4 (&wv)[16], const u64* zin64,
                                  u64* zout64, float bias) {
                    consume_z(zin64, tagbase + R, z_s, t);
                    float acc = 0.f;
                    #pragma unroll
                    for (int i = 0; i < 16; i++) {
                        float4 zv = *(const float4*)(z_s + (laneH * 4 + i * 64));
                        acc = fmaf(wv[i].x, zv.x, acc);
                        acc = fmaf(wv[i].y, zv.y, acc);
                        acc = fmaf(wv[i].z, zv.z, acc);
                        acc = fmaf(wv[i].w, zv.w, acc);
                    }
                    #pragma unroll
                    for (int m = 1; m < 16; m <<= 1) acc += __shfl_xor(acc, m, 16);
                    float val = softplus_f(acc + bias);
                    float vodd = __shfl(val, (t & 63) + 16, 64);
                    ++R;
                    if ((t & 31) == 0) st_pack(&zout64[packIdx], val, vodd, tagbase + R);
                };

                hidden(wv0, zA64, zB64, bhr[0]);
                hidden(wv1, zB64, zA64, bhr[1]);

                // prefetch Wl row slice (L2-resident); overlaps h3 exchange
                float4 wvL[4];
                #pragma unroll
                for (int i = 0; i < 4; i++) wvL[i] = *(const float4*)(wlp + i * 256);

                // ---- h3: weights from LDS (fmaf-pinned) ----
                {
                    consume_z(zA64, tagbase + R, z_s, t);
                    const float* wr = wh2 + rowH * WID + laneH * 4;
                    float acc = 0.f;
                    #pragma unroll
                    for (int i = 0; i < 16; i++) {
                        float4 wv4 = *(const float4*)(wr + i * 64);
                        float4 zv  = *(const float4*)(z_s + (laneH * 4 + i * 64));
                        acc = fmaf(wv4.x, zv.x, acc);
                        acc = fmaf(wv4.y, zv.y, acc);
                        acc = fmaf(wv4.z, zv.z, acc);
                        acc = fmaf(wv4.w, zv.w, acc);
                    }
                    #pragma unroll
                    for (int m = 1; m < 16; m <<= 1) acc += __shfl_xor(acc, m, 16);
                    float val = softplus_f(acc + bhr[2]);
                    float vodd = __shfl(val, (t & 63) + 16, 64);
                    ++R;
                    if ((t & 31) == 0) st_pack(&zB64[packIdx], val, vodd, tagbase + R);
                }

                // ---- Wl: 256x1024, 8 rows/block; tanh; dh published f32 ----
                {
                    consume_z(zB64, tagbase + R, z_s, t);
                    float acc = 0.f;
                    #pragma unroll
                    for (int i = 0; i < 4; i++) {
                        float4 zv = *(const float4*)(z_s + (laneL * 4 + i * 256));
                        acc = fmaf(wvL[i].x, zv.x, acc);
                        acc = fmaf(wvL[i].y, zv.y, acc);
                        acc = fmaf(wvL[i].z, zv.z, acc);
                        acc = fmaf(wvL[i].w, zv.w, acc);
                    }
                    #pragma unroll
                    for (int m = 1; m < 64; m <<= 1) acc += __shfl_xor(acc, m, 64);
                    ++R;
                    if (laneL == 0)
                        st_tag(&dh64[growL], scale0 * tanhf(0.01f * (acc + blr)), tagbase + R);
                }

                // ---- gather dh (f32, one word per thread t<256) ----
                {
                    if (t < NH) {
                        u64 w; int it = 0;
                        do { w = ld_tag(dh64 + t); }
                        while (!tag_ok(w, tagbase + R) && ++it < POLL_CAP);
                        k_s[NSTATE + t] = __uint_as_float((u32)w);
                    }
                    __syncthreads();
                    if (t < NX) yn_s[t] = fmaf(wgt, k_s[t], yn_s[t]);
                }
            } // stages

            __syncthreads();
            if (t < NX) y_s[t] = yn_s[t];
            __syncthreads();
        } // substeps

        if (blk == 0) {
            if (t < NSTATE) out[(iv + 1) * NSTATE + t] = y_s[t];
            if (t < NH)     out[NT * NSTATE + (iv + 1) * NH + t] = y_s[NSTATE + t];
        }
    } // intervals
}

extern "C" void kernel_launch(void* const* d_in, const int* in_sizes, int n_in,
                              void* d_out, int out_size, void* d_ws, size_t ws_size,
                              hipStream_t stream) {
    const float* ts    = (const float*)d_in[0];
    const float* W0    = (const float*)d_in[1];
    const float* b0    = (const float*)d_in[2];
    const float* Wh    = (const float*)d_in[3];
    const float* bh    = (const float*)d_in[4];
    const float* Wl    = (const float*)d_in[5];
    const float* bl    = (const float*)d_in[6];
    const float* betaW = (const float*)d_in[7];
    const float* betab = (const float*)d_in[8];
    const float* hvec  = (const float*)d_in[9];
    const float* scale = (const float*)d_in[10];
    const float* y0log = (const float*)d_in[11];
    float* out = (float*)d_out;

    u64*      zA64 = (u64*)d_ws;                          // 512*8 = 4 KB
    u64*      zB64 = (u64*)((char*)d_ws + 4096);          // 4 KB
    u64*      dh64 = (u64*)((char*)d_ws + 8192);          // 256*8 = 2 KB
    unsigned* ctrl = (unsigned*)((char*)d_ws + 10240);    // cnt[8], winner word

    // allow 128KB dynamic LDS (h3 weight slice)
    static int lds_set = 0;
    if (!lds_set) {
        hipFuncSetAttribute((const void*)ode_kernel,
                            hipFuncAttributeMaxDynamicSharedMemorySize, 131072);
        lds_set = 1;
    }

    // zero tagged words + election state (tag 0 never matches nonce+R)
    hipMemsetAsync(d_ws, 0, 10240 + 64, stream);
    hipLaunchKernelGGL(ode_kernel, dim3(NLAUNCH), dim3(BS), 131072, stream,
                       ts, W0, b0, Wh, bh, Wl, bl, betaW, betab, hvec, scale,
                       y0log, out, zA64, zB64, dh64, ctrl);
}